// Round 11
// baseline (639.205 us; speedup 1.0000x reference)
//
#include <hip/hip_runtime.h>
#include <hip/hip_bf16.h>
#include <cstdint>

// Problem constants (fixed by the reference).
static constexpr int N = 100000;
static constexpr int E = 3200000;
static constexpr float BN_EPS = 1e-5f;
static constexpr int NBUCK = (N + 127) >> 7;   // 782 buckets of 128 nodes
static constexpr int NBLK = 256;               // edge-counting blocks
static constexpr int CHUNK = E / NBLK;         // 12500 edges per block (exact)

// Aggregation: wave owns 8 nodes; wave's WHOLE edge set sorted slice-major
// (slice = col>>13 -> XCD L2 phase lock). 2-deep pipeline with REAL counted
// vmcnt: gathers are inline-asm global_load_dword (saddr form) so the compiler
// can neither sink nor auto-wait them; we drain with s_waitcnt vmcnt(8) so the
// other batch's 8 loads stay in flight. r10 lesson: asm loads are invisible to
// the compiler's waitcnt pass -> MUST manually vmcnt(0) at loop exit, else
// in-flight loads clobber reallocated VGPRs in the epilogue (GPU fault).
// NO LDS atomics (gfx950 LDS fp atomics ~190cy/instr, r2/r6).
// Padded per wave to %16; epk = Tbyteoff|dloc.
static constexpr int NPW = 8;                          // nodes per wave
static constexpr int NW2 = N / NPW;                    // 12500 (exact)
static constexpr int AGG2_BLOCKS = NW2 / 4;            // 3125 (exact)
static constexpr int NSLICE = ((N - 1) >> 13) + 1;     // 13
static constexpr int NBKT = NSLICE * NPW;              // 104 buckets/wave
static constexpr int BNRED_PER = (AGG2_BLOCKS + 63) / 64; // 49

// ---------------- workspace layout ----------------
static constexpr size_t OFF_TOT_D = 0;              // NBUCK int
static constexpr size_t OFF_TOT_S = 3328;           // NBUCK int
static constexpr size_t OFF_DBASE = 6656;           // NBUCK+1 int
static constexpr size_t OFF_SBASE = 9984;           // NBUCK+1 int
static constexpr size_t OFF_CVEC  = 15360;          // 128 f32
static constexpr size_t OFF_WT    = 16384;          // 128*128 bf16
static constexpr size_t OFF_PBASE = 49152;          // NBUCK+1 int (padded bucket bases)
static constexpr size_t OFF_PTOT  = 53248;          // NBUCK int (padded bucket totals)
static constexpr size_t OFF_BNP2  = 82944;          // 64*256 f32 (ends 148480)
static constexpr size_t OFF_EB    = 149504;         // (16*NBUCK+1) int per-wave padded bases
static constexpr size_t OFF_NORM_S= 2245632;        // N f32
static constexpr size_t OFF_NORM_D= 2645632;        // N f32
static constexpr size_t OFF_RP    = 3045632;        // N+1 int
static constexpr size_t OFF_CNT_D = 3445760;        // NBLK*NBUCK int; reused as bnp
static constexpr size_t OFF_BNP   = OFF_CNT_D;      // AGG2_BLOCKS*256 f32 = 3.2MB
static constexpr size_t OFF_CNT_S = 4246528;        // NBLK*NBUCK int
static constexpr size_t OFF_OFFD  = 5047296;        // NBLK*NBUCK int
static constexpr size_t OFF_OFFS  = 5848064;        // NBLK*NBUCK int
static constexpr size_t OFF_COL   = 6648832;        // E int (6648832..19448832)
static constexpr size_t OFF_EPK   = 19448832;       // padded edge stream; cap
                                                    // 4*(E+15*NW2)=13.55MB < 15.6MB region
static constexpr size_t OFF_SRCB  = 19448832;       // E uchar (dead after build; epk reuses)
static constexpr size_t OFF_PAIRS = 22648832;       // E uint (dead after build; epk spills in)
static constexpr size_t OFF_H     = 35448832;       // N*128 bf16
static constexpr size_t OFF_T     = 61048832;       // N*128 bf16
static constexpr unsigned T_OFFU  = 61048832u;
// Dummy rows: P_DUMMY in the col region (dead after k_eprep); its 64f image
// (P_DUMMY>>1)+C64 in the dead gap [35048832,35448832). Low 8 bits of P_DUMMY = 0
// (dloc 0 -> adds +0.0f to node n0: harmless). Zeroed by layer-1 k_wprep block 0.
static constexpr unsigned P_DUMMY  = 9437184u;      // 256B zero row (ws-relative)
static constexpr unsigned C64      = 30524416u;     // OFF_T/2 : agg64 rebase
static constexpr size_t OFF_DUM128 = 9437184;       // == P_DUMMY
static constexpr size_t OFF_DUM64  = 35243008;      // == (P_DUMMY>>1)+C64

using short8  = __attribute__((ext_vector_type(8))) short;
using float4v = __attribute__((ext_vector_type(4))) float;

__device__ inline float bflo(unsigned v) { return __uint_as_float(v << 16); }
__device__ inline float bfhi(unsigned v) { return __uint_as_float(v & 0xffff0000u); }
__device__ inline unsigned short bfbits(float x) {
    __hip_bfloat16 h = __float2bfloat16(x);
    return *reinterpret_cast<unsigned short*>(&h);
}

// ---- pass 1: per-block privatized bucket histograms (LDS atomics only) ----
__global__ __launch_bounds__(256) void k_count(const int* __restrict__ src,
                                               const int* __restrict__ dst,
                                               int* __restrict__ cnt_s,
                                               int* __restrict__ cnt_d) {
    __shared__ int hs[NBUCK], hd[NBUCK];
    int tid = threadIdx.x, blk = blockIdx.x;
    for (int b = tid; b < NBUCK; b += 256) { hs[b] = 0; hd[b] = 0; }
    __syncthreads();
    int e0 = blk * CHUNK, e1 = min(E, e0 + CHUNK);
    for (int e = e0 + tid; e < e1; e += 256) {
        atomicAdd(&hs[src[e] >> 7], 1);
        atomicAdd(&hd[dst[e] >> 7], 1);
    }
    __syncthreads();
    for (int b = tid; b < NBUCK; b += 256) {
        cnt_s[blk * NBUCK + b] = hs[b];
        cnt_d[blk * NBUCK + b] = hd[b];
    }
}

// ---- pass 2a: per-bucket scan over the 256 counting blocks ----
__global__ __launch_bounds__(256) void k_scanA2(const int* __restrict__ cnt_d,
                                                const int* __restrict__ cnt_s,
                                                int* __restrict__ offd,
                                                int* __restrict__ offs,
                                                int* __restrict__ tot_d,
                                                int* __restrict__ tot_s) {
    __shared__ int sd[256];
    int which = (blockIdx.x >= NBUCK) ? 1 : 0;
    int b = blockIdx.x - which * NBUCK;
    const int* cnt = which ? cnt_s : cnt_d;
    int* off = which ? offs : offd;
    int* tot = which ? tot_s : tot_d;
    int tid = threadIdx.x;
    int v = cnt[tid * NBUCK + b];
    sd[tid] = v;
    __syncthreads();
    for (int o = 1; o < 256; o <<= 1) {
        int t = (tid >= o) ? sd[tid - o] : 0;
        __syncthreads();
        sd[tid] += t;
        __syncthreads();
    }
    off[tid * NBUCK + b] = sd[tid] - v;
    if (tid == 255) tot[b] = sd[255];
}

// ---- pass 2b: scan bucket totals -> bases ----
__global__ __launch_bounds__(1024) void k_scanB(const int* __restrict__ tot_d,
                                                const int* __restrict__ tot_s,
                                                int* __restrict__ dbase,
                                                int* __restrict__ sbase) {
    __shared__ int sd[1024], ss[1024];
    int tid = threadIdx.x;
    int vd = (tid < NBUCK) ? tot_d[tid] : 0;
    int vs = (tid < NBUCK) ? tot_s[tid] : 0;
    sd[tid] = vd; ss[tid] = vs;
    __syncthreads();
    for (int o = 1; o < 1024; o <<= 1) {
        int td = (tid >= o) ? sd[tid - o] : 0;
        int ts = (tid >= o) ? ss[tid - o] : 0;
        __syncthreads();
        sd[tid] += td; ss[tid] += ts;
        __syncthreads();
    }
    if (tid < NBUCK) { dbase[tid] = sd[tid] - vd; sbase[tid] = ss[tid] - vs; }
    if (tid == 0) { dbase[NBUCK] = E; sbase[NBUCK] = E; }
}

// ---- pass 3: deterministic-offset scatter ----
__global__ __launch_bounds__(256) void k_scatter(const int* __restrict__ src,
                                                 const int* __restrict__ dst,
                                                 const int* __restrict__ dbase,
                                                 const int* __restrict__ sbase,
                                                 const int* __restrict__ offd,
                                                 const int* __restrict__ offs,
                                                 unsigned* __restrict__ pairs,
                                                 unsigned char* __restrict__ srcb) {
    __shared__ int cd[NBUCK], cs[NBUCK];
    int tid = threadIdx.x, blk = blockIdx.x;
    for (int b = tid; b < NBUCK; b += 256) {
        cd[b] = dbase[b] + offd[blk * NBUCK + b];
        cs[b] = sbase[b] + offs[blk * NBUCK + b];
    }
    __syncthreads();
    int e0 = blk * CHUNK, e1 = min(E, e0 + CHUNK);
    for (int e = e0 + tid; e < e1; e += 256) {
        int s = src[e], d = dst[e];
        int pd = atomicAdd(&cd[d >> 7], 1);
        pairs[pd] = (unsigned)s | ((unsigned)(d & 127) << 20);
        int ps = atomicAdd(&cs[s >> 7], 1);
        srcb[ps] = (unsigned char)(s & 127);
    }
}

// ---- pass 4: per-bucket degrees/norms/rp/col + per-wave padded bases ----
__global__ __launch_bounds__(256) void k_build(const unsigned* __restrict__ pairs,
                                               const unsigned char* __restrict__ srcb,
                                               const int* __restrict__ dbase,
                                               const int* __restrict__ sbase,
                                               int* __restrict__ rp,
                                               float* __restrict__ norm_d,
                                               float* __restrict__ norm_s,
                                               int* __restrict__ col,
                                               int* __restrict__ eb,
                                               int* __restrict__ ptot) {
    __shared__ int cnt[128], scn[128], lcur[128];
    __shared__ int wpe[16], wps[16];
    int b = blockIdx.x, tid = threadIdx.x, node0 = b << 7;
    int nmax = min(128, N - node0);
    if (tid < 128) cnt[tid] = 0;
    __syncthreads();
    int sb = sbase[b], se = sbase[b + 1];
    for (int e = sb + tid; e < se; e += 256) atomicAdd(&cnt[srcb[e]], 1);
    __syncthreads();
    if (tid < nmax) norm_s[node0 + tid] = rsqrtf(fmaxf((float)cnt[tid], 1.0f));
    __syncthreads();
    if (tid < 128) cnt[tid] = 0;
    __syncthreads();
    int beg = dbase[b], end = dbase[b + 1];
    for (int e = beg + tid; e < end; e += 256) atomicAdd(&cnt[pairs[e] >> 20], 1);
    __syncthreads();
    if (tid < 128) scn[tid] = cnt[tid];
    if (tid < 16) {   // per-wave (8-node chunk) padded totals (%16 for 2-deep pipeline)
        int s = 0;
#pragma unroll
        for (int i = 0; i < 8; ++i) s += cnt[tid * 8 + i];
        wpe[tid] = (s + 15) & ~15;
    }
    __syncthreads();
    for (int o = 1; o < 128; o <<= 1) {
        int t = (tid < 128 && tid >= o) ? scn[tid - o] : 0;
        __syncthreads();
        if (tid < 128) scn[tid] += t;
        __syncthreads();
    }
    if (tid == 0) {
        int run = 0;
#pragma unroll
        for (int k = 0; k < 16; ++k) { int c = wpe[k]; wps[k] = run; run += c; }
        ptot[b] = run;
    }
    __syncthreads();
    if (tid < 16) eb[b * 16 + tid] = wps[tid];      // local padded excl (finalized in eprep)
    if (tid < nmax) {
        int excl = beg + scn[tid] - cnt[tid];
        rp[node0 + tid] = excl;
        lcur[tid] = excl;
        norm_d[node0 + tid] = rsqrtf(fmaxf((float)cnt[tid], 1.0f));
    }
    if (b == 0 && tid == 0) rp[N] = E;
    __syncthreads();
    for (int e = beg + tid; e < end; e += 256) {
        unsigned p = pairs[e];
        int pos = atomicAdd(&lcur[p >> 20], 1);
        col[pos] = (int)(p & 0xFFFFFu);
    }
}

// ---- scan padded bucket totals -> pbase; finalize eb[NW2] ----
__global__ __launch_bounds__(1024) void k_scanP(const int* __restrict__ ptot,
                                                int* __restrict__ pbase,
                                                int* __restrict__ eb) {
    __shared__ int sd[1024];
    int tid = threadIdx.x;
    int v = (tid < NBUCK) ? ptot[tid] : 0;
    sd[tid] = v;
    __syncthreads();
    for (int o = 1; o < 1024; o <<= 1) {
        int t = (tid >= o) ? sd[tid - o] : 0;
        __syncthreads();
        sd[tid] += t;
        __syncthreads();
    }
    if (tid < NBUCK) pbase[tid] = sd[tid] - v;
    if (tid == 1023) { pbase[NBUCK] = sd[1023]; eb[NW2] = sd[1023]; }
}

// ---- edge prep: per-wave (slice,dloc)-sorted padded segment ----
// epk = T_OFF + col*256 + dloc ; wave-set slice-major order = L2 phase lock.
__global__ __launch_bounds__(256) void k_eprep(const int* __restrict__ col,
                                               const int* __restrict__ rp,
                                               const int* __restrict__ pbase,
                                               int* __restrict__ eb,
                                               unsigned* __restrict__ epk) {
    __shared__ int cnt[4][NBKT];
    int tid = threadIdx.x, wave = tid >> 6, lane = tid & 63;
    int w = blockIdx.x * 4 + wave;
    int n0 = w * NPW;
    for (int k = lane; k < NBKT; k += 64) cnt[wave][k] = 0;
    int rpl[NPW + 1];
#pragma unroll
    for (int j = 0; j <= NPW; ++j) rpl[j] = rp[n0 + j];
    // per-wave private LDS + in-order DS pipe -> no barriers needed
#pragma unroll
    for (int j = 0; j < NPW; ++j)
        for (int e = rpl[j] + lane; e < rpl[j + 1]; e += 64)
            atomicAdd(&cnt[wave][(((unsigned)col[e]) >> 13) * NPW + j], 1);
    if (lane == 0) {
        int base = pbase[n0 >> 7] + eb[w];
        eb[w] = base;                                  // finalize global padded base
        int run = base;
        for (int k = 0; k < NBKT; ++k) { int c = cnt[wave][k]; cnt[wave][k] = run; run += c; }
        int padend = base + ((rpl[NPW] - rpl[0] + 15) & ~15);
        for (int q = run; q < padend; ++q) epk[q] = P_DUMMY;
    }
#pragma unroll
    for (int j = 0; j < NPW; ++j)
        for (int e = rpl[j] + lane; e < rpl[j + 1]; e += 64) {
            unsigned c = (unsigned)col[e];
            int pos = atomicAdd(&cnt[wave][(c >> 13) * NPW + j], 1);
            epk[pos] = T_OFFU + (c << 8) + (unsigned)j;
        }
}

// ---- W prep (fused BN finalize); layer-1 instance also zeroes the dummy rows ----
template <bool AFFINE>
__global__ __launch_bounds__(64) void k_wprep(const float* __restrict__ W,
                                              const float* __restrict__ part2, // 64 x 256
                                              const float* __restrict__ gamma,
                                              const float* __restrict__ beta,
                                              int fout,
                                              unsigned short* __restrict__ Wt,
                                              float* __restrict__ cvec,
                                              unsigned* __restrict__ dz256,
                                              unsigned* __restrict__ dz64) {
    int n = blockIdx.x, k = threadIdx.x;
    if (!AFFINE && n == 0) {
        dz256[k] = 0u;                 // 64 uints = 256 B @ OFF_DUM128
        if (k < 32) dz64[k] = 0u;      // 32 uints = 128 B @ OFF_DUM64
    }
    float a0 = 1.f, c0 = 0.f, a1 = 1.f, c1 = 0.f;
    if (AFFINE) {
        int l0 = ((k & 1) ? 128 : 0) + (k >> 1);
        int m0 = ((k & 1) ? 192 : 64) + (k >> 1);
        int l1 = l0 + 32, m1 = m0 + 32;
        float s0 = 0.f, q0 = 0.f, s1 = 0.f, q1 = 0.f;
        for (int b = 0; b < 64; ++b) {
            const float* r = part2 + b * 256;
            s0 += r[l0]; q0 += r[m0];
            s1 += r[l1]; q1 += r[m1];
        }
        float mu0 = s0 * (1.0f / N), var0 = q0 * (1.0f / N) - mu0 * mu0;
        a0 = gamma[k] * rsqrtf(var0 + BN_EPS);
        c0 = beta[k] - mu0 * a0;
        float mu1 = s1 * (1.0f / N), var1 = q1 * (1.0f / N) - mu1 * mu1;
        a1 = gamma[k + 64] * rsqrtf(var1 + BN_EPS);
        c1 = beta[k + 64] - mu1 * a1;
    }
    float w0 = W[k * fout + n], w1 = W[(k + 64) * fout + n];
    Wt[n * 128 + k] = bfbits(a0 * w0);
    Wt[n * 128 + k + 64] = bfbits(a1 * w1);
    float cv = c0 * w0 + c1 * w1;
    for (int o = 32; o; o >>= 1) cv += __shfl_xor(cv, o);
    if (k == 0) cvec[n] = cv;
}

// ---- MFMA GEMM: T = ns .* (Xbf16 @ Wt^T + cvec) ----
template <typename TIn, int FOUT>
__global__ __launch_bounds__(256) void k_gemm(const TIn* __restrict__ in,
                                              const unsigned short* __restrict__ Wt,
                                              const float* __restrict__ cvec,
                                              const float* __restrict__ ns,
                                              unsigned short* __restrict__ out) {
    constexpr int PK = 72;
    __shared__ __align__(16) unsigned short Xs[128 * PK];
    __shared__ __align__(16) unsigned short Wsh[FOUT * PK];
    const int tid = threadIdx.x;
    const int r0 = blockIdx.x * 128;
    const int wave = tid >> 6, lane = tid & 63;
    const int l16 = lane & 15, quad = lane >> 4;
    constexpr int MT = (FOUT == 128) ? 4 : 2;
    constexpr int NT = 4;
    const int wm = (FOUT == 128) ? (wave >> 1) : wave;
    const int wn = (FOUT == 128) ? (wave & 1) : 0;
    const int mbase = wm * (MT * 16);
    const int nbase = wn * 64;

    float4v acc[MT][NT];
#pragma unroll
    for (int mt = 0; mt < MT; ++mt)
#pragma unroll
        for (int nt = 0; nt < NT; ++nt) acc[mt][nt] = (float4v){0.f, 0.f, 0.f, 0.f};

    for (int kb = 0; kb < 128; kb += 64) {
        __syncthreads();
        for (int i = tid; i < 128 * 8; i += 256) {
            int row = i >> 3, j = i & 7;
            int grow = r0 + row;
            if constexpr (sizeof(TIn) == 4) {
                short8 p = {0, 0, 0, 0, 0, 0, 0, 0};
                if (grow < N) {
                    const float* g = (const float*)in + (size_t)grow * 128 + kb + j * 8;
                    float4 f0 = *(const float4*)g;
                    float4 f1 = *(const float4*)(g + 4);
                    p[0] = (short)bfbits(f0.x); p[1] = (short)bfbits(f0.y);
                    p[2] = (short)bfbits(f0.z); p[3] = (short)bfbits(f0.w);
                    p[4] = (short)bfbits(f1.x); p[5] = (short)bfbits(f1.y);
                    p[6] = (short)bfbits(f1.z); p[7] = (short)bfbits(f1.w);
                }
                *(short8*)&Xs[row * PK + j * 8] = p;
            } else {
                uint4 v = make_uint4(0, 0, 0, 0);
                if (grow < N)
                    v = *(const uint4*)((const unsigned short*)in + (size_t)grow * 128 + kb + j * 8);
                *(uint4*)&Xs[row * PK + j * 8] = v;
            }
        }
        for (int i = tid; i < FOUT * 8; i += 256) {
            int n = i >> 3, j = i & 7;
            uint4 v = *(const uint4*)&Wt[n * 128 + kb + j * 8];
            *(uint4*)&Wsh[n * PK + j * 8] = v;
        }
        __syncthreads();
#pragma unroll
        for (int ks = 0; ks < 64; ks += 32) {
            short8 af[MT], bfr[NT];
#pragma unroll
            for (int mt = 0; mt < MT; ++mt)
                af[mt] = *(const short8*)&Xs[(mbase + mt * 16 + l16) * PK + ks + quad * 8];
#pragma unroll
            for (int nt = 0; nt < NT; ++nt)
                bfr[nt] = *(const short8*)&Wsh[(nbase + nt * 16 + l16) * PK + ks + quad * 8];
#pragma unroll
            for (int mt = 0; mt < MT; ++mt)
#pragma unroll
                for (int nt = 0; nt < NT; ++nt)
                    acc[mt][nt] = __builtin_amdgcn_mfma_f32_16x16x32_bf16(
                        af[mt], bfr[nt], acc[mt][nt], 0, 0, 0);
        }
    }
    float cv[NT];
#pragma unroll
    for (int nt = 0; nt < NT; ++nt) cv[nt] = cvec[nbase + nt * 16 + l16];
#pragma unroll
    for (int mt = 0; mt < MT; ++mt) {
#pragma unroll
        for (int r = 0; r < 4; ++r) {
            int row = r0 + mbase + mt * 16 + quad * 4 + r;
            if (row < N) {
                float s = ns[row];
#pragma unroll
                for (int nt = 0; nt < NT; ++nt)
                    out[(size_t)row * FOUT + nbase + nt * 16 + l16] =
                        bfbits((acc[mt][nt][r] + cv[nt]) * s);
            }
        }
    }
}

// ------- aggregation (128 feats): slice-major wave set; asm-load 2-deep pipeline -------
__global__ __launch_bounds__(256, 8) void k_agg128s(const char* wsb,
                                                    const int* __restrict__ eb,
                                                    const unsigned* __restrict__ epk,
                                                    const float* __restrict__ norm_d,
                                                    const float* __restrict__ bias,
                                                    unsigned* Hu,          // N x 64 uints
                                                    float* __restrict__ part) {
    // acc[wave][dloc]: float2 per lane (feats 2l, 2l+1)
    __shared__ float acc[4][NPW][128];                // 16 KB; red overlays later
    const int tid = threadIdx.x, wave = tid >> 6, lane = tid & 63;
    const int w = blockIdx.x * 4 + wave;
    const int n0 = w * NPW;
    float2* a2 = reinterpret_cast<float2*>(&acc[wave][0][0]) + lane; // a2[dloc*64]
#pragma unroll
    for (int j = 0; j < NPW; ++j) a2[j * 64] = make_float2(0.f, 0.f);
    const unsigned lane4 = (unsigned)(lane << 2);
    int e = __builtin_amdgcn_readfirstlane(eb[w]);
    const int e1 = __builtin_amdgcn_readfirstlane(eb[w + 1]);
    int cur = 0;
    float a0 = 0.f, a1 = 0.f;
    if (e < e1) {
        unsigned pa[8], pb[8];
        int da[8], db[8];
        unsigned va[8], vb[8];
        // prologue: issue batch A (asm loads: unsinkable, untracked by waitcnt pass)
#pragma unroll
        for (int i = 0; i < 8; ++i) pa[i] = epk[e + i];
#pragma unroll
        for (int i = 0; i < 8; ++i) da[i] = __builtin_amdgcn_readfirstlane((int)(pa[i] & 7u));
#pragma unroll
        for (int i = 0; i < 8; ++i) {
            unsigned off = (pa[i] & 0xFFFFFF00u) + lane4;
            asm volatile("global_load_dword %0, %1, %2"
                         : "=v"(va[i]) : "v"(off), "s"(wsb));
        }
        for (; e + 16 <= e1; e += 16) {
            // issue batch B (8 loads -> in flight across A's processing)
#pragma unroll
            for (int i = 0; i < 8; ++i) pb[i] = epk[e + 8 + i];
#pragma unroll
            for (int i = 0; i < 8; ++i) db[i] = __builtin_amdgcn_readfirstlane((int)(pb[i] & 7u));
#pragma unroll
            for (int i = 0; i < 8; ++i) {
                unsigned off = (pb[i] & 0xFFFFFF00u) + lane4;
                asm volatile("global_load_dword %0, %1, %2"
                             : "=v"(vb[i]) : "v"(off), "s"(wsb));
            }
            // counted drain: A complete, B's 8 stay outstanding
            asm volatile("s_waitcnt vmcnt(8)" ::: "memory");
            __builtin_amdgcn_sched_barrier(0);
#pragma unroll
            for (int i = 0; i < 8; ++i) {
                if (da[i] != cur) {                   // wave-uniform scalar branch
                    float2 t = a2[cur * 64]; t.x += a0; t.y += a1; a2[cur * 64] = t;
                    cur = da[i]; a0 = 0.f; a1 = 0.f;
                }
                a0 += bflo(va[i]); a1 += bfhi(va[i]);
            }
            __builtin_amdgcn_sched_barrier(0);
            // issue next batch A (clamped on final iteration; never processed then)
            {
                int en = (e + 16 < e1) ? (e + 16) : (e1 - 8);
#pragma unroll
                for (int i = 0; i < 8; ++i) pa[i] = epk[en + i];
#pragma unroll
                for (int i = 0; i < 8; ++i) da[i] = __builtin_amdgcn_readfirstlane((int)(pa[i] & 7u));
#pragma unroll
                for (int i = 0; i < 8; ++i) {
                    unsigned off = (pa[i] & 0xFFFFFF00u) + lane4;
                    asm volatile("global_load_dword %0, %1, %2"
                                 : "=v"(va[i]) : "v"(off), "s"(wsb));
                }
            }
            // counted drain: B complete, A's 8 stay outstanding
            asm volatile("s_waitcnt vmcnt(8)" ::: "memory");
            __builtin_amdgcn_sched_barrier(0);
#pragma unroll
            for (int i = 0; i < 8; ++i) {
                if (db[i] != cur) {
                    float2 t = a2[cur * 64]; t.x += a0; t.y += a1; a2[cur * 64] = t;
                    cur = db[i]; a0 = 0.f; a1 = 0.f;
                }
                a0 += bflo(vb[i]); a1 += bfhi(vb[i]);
            }
            __builtin_amdgcn_sched_barrier(0);
        }
        // r10 fix: drain ALL asm loads (final speculative A' batch) before the
        // epilogue — their dest VGPRs get reallocated; late returns clobber them.
        asm volatile("s_waitcnt vmcnt(0)" ::: "memory");
        __builtin_amdgcn_sched_barrier(0);
        // final run flush
        float2 t = a2[cur * 64]; t.x += a0; t.y += a1; a2[cur * 64] = t;
    }
    // epilogue: per-node outputs + BN partials (own wave's acc only)
    float s0 = 0.f, q0 = 0.f, s1 = 0.f, q1 = 0.f;
    const float bb0 = bias[2 * lane], bb1 = bias[2 * lane + 1];
#pragma unroll
    for (int j = 0; j < NPW; ++j) {
        int n = n0 + j;
        float2 a = a2[j * 64];
        float nd = norm_d[n];
        float r0 = fmaxf(a.x * nd + bb0, 0.0f);
        float r1 = fmaxf(a.y * nd + bb1, 0.0f);
        Hu[(size_t)n * 64 + lane] = ((unsigned)bfbits(r1) << 16) | bfbits(r0);
        s0 += r0; q0 += r0 * r0; s1 += r1; q1 += r1 * r1;
    }
    __syncthreads();                     // everyone done reading their acc
    float* red = &acc[0][0][0];          // reuse first 1024 floats as reduce stage
    red[wave * 256 + lane] = s0;
    red[wave * 256 + 64 + lane] = q0;
    red[wave * 256 + 128 + lane] = s1;
    red[wave * 256 + 192 + lane] = q1;
    __syncthreads();
    float t = red[tid] + red[256 + tid] + red[512 + tid] + red[768 + tid];
    part[blockIdx.x * 256 + tid] = t;
}

// hierarchical BN partial reduce: AGG2_BLOCKS rows -> 64 rows
__global__ __launch_bounds__(256) void k_bnred(const float* __restrict__ part,
                                               float* __restrict__ part2) {
    int b = blockIdx.x, tid = threadIdx.x;
    float s = 0.f;
    for (int i = 0; i < BNRED_PER; ++i) {
        int r = b * BNRED_PER + i;
        if (r < AGG2_BLOCKS) s += part[r * 256 + tid];
    }
    part2[b * 256 + tid] = s;
}

// ------- aggregation (64 feats) + log_softmax: same asm-load pipelined structure -------
__global__ __launch_bounds__(256, 8) void k_agg64s(const char* wsb,
                                                   const int* __restrict__ eb,
                                                   const unsigned* __restrict__ epk,
                                                   const float* __restrict__ norm_d,
                                                   const float* __restrict__ b3,
                                                   float* __restrict__ out) {
    __shared__ float acc[4][NPW][64];                 // 8 KB
    const int tid = threadIdx.x, wave = tid >> 6, lane = tid & 63;
    const int w = blockIdx.x * 4 + wave;
    const int n0 = w * NPW;
    float* a1p = &acc[wave][0][0] + lane;             // a1p[dloc*64]
#pragma unroll
    for (int j = 0; j < NPW; ++j) a1p[j * 64] = 0.f;
    const unsigned lane2 = (unsigned)(lane << 1);
    int e = __builtin_amdgcn_readfirstlane(eb[w]);
    const int e1 = __builtin_amdgcn_readfirstlane(eb[w + 1]);
    int cur = 0;
    float a0 = 0.f;
    if (e < e1) {
        unsigned pa[8], pb[8];
        int da[8], db[8];
        unsigned ua[8], ub[8];
#pragma unroll
        for (int i = 0; i < 8; ++i) pa[i] = epk[e + i];
#pragma unroll
        for (int i = 0; i < 8; ++i) da[i] = __builtin_amdgcn_readfirstlane((int)(pa[i] & 7u));
#pragma unroll
        for (int i = 0; i < 8; ++i) {
            unsigned off = ((pa[i] >> 1) & 0xFFFFFF80u) + C64 + lane2;
            asm volatile("global_load_ushort %0, %1, %2"
                         : "=v"(ua[i]) : "v"(off), "s"(wsb));
        }
        for (; e + 16 <= e1; e += 16) {
#pragma unroll
            for (int i = 0; i < 8; ++i) pb[i] = epk[e + 8 + i];
#pragma unroll
            for (int i = 0; i < 8; ++i) db[i] = __builtin_amdgcn_readfirstlane((int)(pb[i] & 7u));
#pragma unroll
            for (int i = 0; i < 8; ++i) {
                unsigned off = ((pb[i] >> 1) & 0xFFFFFF80u) + C64 + lane2;
                asm volatile("global_load_ushort %0, %1, %2"
                             : "=v"(ub[i]) : "v"(off), "s"(wsb));
            }
            asm volatile("s_waitcnt vmcnt(8)" ::: "memory");
            __builtin_amdgcn_sched_barrier(0);
#pragma unroll
            for (int i = 0; i < 8; ++i) {
                if (da[i] != cur) { a1p[cur * 64] += a0; cur = da[i]; a0 = 0.f; }
                a0 += __uint_as_float(ua[i] << 16);
            }
            __builtin_amdgcn_sched_barrier(0);
            {
                int en = (e + 16 < e1) ? (e + 16) : (e1 - 8);
#pragma unroll
                for (int i = 0; i < 8; ++i) pa[i] = epk[en + i];
#pragma unroll
                for (int i = 0; i < 8; ++i) da[i] = __builtin_amdgcn_readfirstlane((int)(pa[i] & 7u));
#pragma unroll
                for (int i = 0; i < 8; ++i) {
                    unsigned off = ((pa[i] >> 1) & 0xFFFFFF80u) + C64 + lane2;
                    asm volatile("global_load_ushort %0, %1, %2"
                                 : "=v"(ua[i]) : "v"(off), "s"(wsb));
                }
            }
            asm volatile("s_waitcnt vmcnt(8)" ::: "memory");
            __builtin_amdgcn_sched_barrier(0);
#pragma unroll
            for (int i = 0; i < 8; ++i) {
                if (db[i] != cur) { a1p[cur * 64] += a0; cur = db[i]; a0 = 0.f; }
                a0 += __uint_as_float(ub[i] << 16);
            }
            __builtin_amdgcn_sched_barrier(0);
        }
        // r10 fix: drain the final speculative A' batch before the epilogue.
        asm volatile("s_waitcnt vmcnt(0)" ::: "memory");
        __builtin_amdgcn_sched_barrier(0);
        a1p[cur * 64] += a0;
    }
    const float bb = b3[lane];
#pragma unroll
    for (int j = 0; j < NPW; ++j) {
        int n = n0 + j;
        float z = a1p[j * 64] * norm_d[n] + bb;
        float m = z;
        for (int o = 32; o; o >>= 1) m = fmaxf(m, __shfl_xor(m, o));
        float ex = __expf(z - m);
        float ssum = ex;
        for (int o = 32; o; o >>= 1) ssum += __shfl_xor(ssum, o);
        out[(size_t)n * 64 + lane] = z - m - __logf(ssum);
    }
}

extern "C" void kernel_launch(void* const* d_in, const int* in_sizes, int n_in,
                              void* d_out, int out_size, void* d_ws, size_t ws_size,
                              hipStream_t stream) {
    const float* x  = (const float*)d_in[0];
    const int* src  = (const int*)d_in[1];
    const int* dst  = (const int*)d_in[2];
    const float* W1 = (const float*)d_in[3];
    const float* b1 = (const float*)d_in[4];
    const float* W2 = (const float*)d_in[5];
    const float* b2 = (const float*)d_in[6];
    const float* W3 = (const float*)d_in[7];
    const float* b3 = (const float*)d_in[8];
    const float* g1 = (const float*)d_in[9];
    const float* be1= (const float*)d_in[10];
    const float* g2 = (const float*)d_in[11];
    const float* be2= (const float*)d_in[12];
    float* out = (float*)d_out;

    char* ws = (char*)d_ws;
    int* tot_d = (int*)(ws + OFF_TOT_D);
    int* tot_s = (int*)(ws + OFF_TOT_S);
    int* dbase = (int*)(ws + OFF_DBASE);
    int* sbase = (int*)(ws + OFF_SBASE);
    float* cvec = (float*)(ws + OFF_CVEC);
    unsigned short* Wt = (unsigned short*)(ws + OFF_WT);
    int* pbase = (int*)(ws + OFF_PBASE);
    int* ptot  = (int*)(ws + OFF_PTOT);
    float* bnp2 = (float*)(ws + OFF_BNP2);
    int* eb = (int*)(ws + OFF_EB);
    float* bnp = (float*)(ws + OFF_BNP);
    float* norm_s = (float*)(ws + OFF_NORM_S);
    float* norm_d = (float*)(ws + OFF_NORM_D);
    int* rp = (int*)(ws + OFF_RP);
    int* cnt_d = (int*)(ws + OFF_CNT_D);
    int* cnt_s = (int*)(ws + OFF_CNT_S);
    int* offd = (int*)(ws + OFF_OFFD);
    int* offs = (int*)(ws + OFF_OFFS);
    int* col = (int*)(ws + OFF_COL);
    unsigned char* srcb = (unsigned char*)(ws + OFF_SRCB);
    unsigned* pairs = (unsigned*)(ws + OFF_PAIRS);
    unsigned* epk = (unsigned*)(ws + OFF_EPK);   // overlays srcb+pairs (dead post-build)
    unsigned* dz256 = (unsigned*)(ws + OFF_DUM128);
    unsigned* dz64  = (unsigned*)(ws + OFF_DUM64);
    unsigned short* H = (unsigned short*)(ws + OFF_H);
    unsigned short* T = (unsigned short*)(ws + OFF_T);

    // CSR build — zero global atomics
    k_count<<<NBLK, 256, 0, stream>>>(src, dst, cnt_s, cnt_d);
    k_scanA2<<<2 * NBUCK, 256, 0, stream>>>(cnt_d, cnt_s, offd, offs, tot_d, tot_s);
    k_scanB<<<1, 1024, 0, stream>>>(tot_d, tot_s, dbase, sbase);
    k_scatter<<<NBLK, 256, 0, stream>>>(src, dst, dbase, sbase, offd, offs, pairs, srcb);
    k_build<<<NBUCK, 256, 0, stream>>>(pairs, srcb, dbase, sbase, rp, norm_d, norm_s, col, eb, ptot);
    k_scanP<<<1, 1024, 0, stream>>>(ptot, pbase, eb);
    k_eprep<<<AGG2_BLOCKS, 256, 0, stream>>>(col, rp, pbase, eb, epk);

    const int gemm_grid = (N + 127) / 128;

    // Layer 1 (wprep block 0 zeroes the dummy rows; runs after eprep, before agg)
    k_wprep<false><<<128, 64, 0, stream>>>(W1, nullptr, nullptr, nullptr, 128, Wt, cvec, dz256, dz64);
    k_gemm<float, 128><<<gemm_grid, 256, 0, stream>>>(x, Wt, cvec, norm_s, T);
    k_agg128s<<<AGG2_BLOCKS, 256, 0, stream>>>(ws, eb, epk, norm_d, b1, (unsigned*)H, bnp);
    k_bnred<<<64, 256, 0, stream>>>(bnp, bnp2);

    // Layer 2 (wprep fuses BN finalize from bnp2)
    k_wprep<true><<<128, 64, 0, stream>>>(W2, bnp2, g1, be1, 128, Wt, cvec, nullptr, nullptr);
    k_gemm<__hip_bfloat16, 128><<<gemm_grid, 256, 0, stream>>>((const __hip_bfloat16*)H, Wt, cvec, norm_s, T);
    k_agg128s<<<AGG2_BLOCKS, 256, 0, stream>>>(ws, eb, epk, norm_d, b2, (unsigned*)H, bnp);
    k_bnred<<<64, 256, 0, stream>>>(bnp, bnp2);

    // Layer 3 (64 outputs) + log_softmax
    k_wprep<true><<<64, 64, 0, stream>>>(W3, bnp2, g2, be2, 64, Wt, cvec, nullptr, nullptr);
    k_gemm<__hip_bfloat16, 64><<<gemm_grid, 256, 0, stream>>>((const __hip_bfloat16*)H, Wt, cvec, norm_s, T);
    k_agg64s<<<AGG2_BLOCKS, 256, 0, stream>>>(ws, eb, epk, norm_d, b3, out);
}

// Round 12
// 594.419 us; speedup vs baseline: 1.0753x; 1.0753x over previous
//
#include <hip/hip_runtime.h>
#include <hip/hip_bf16.h>
#include <cstdint>

// Problem constants (fixed by the reference).
static constexpr int N = 100000;
static constexpr int E = 3200000;
static constexpr float BN_EPS = 1e-5f;
static constexpr int NBUCK = (N + 127) >> 7;   // 782 buckets of 128 nodes
static constexpr int NBLK = 256;               // edge-counting blocks
static constexpr int CHUNK = E / NBLK;         // 12500 edges per block (exact)

// Aggregation: wave owns 8 nodes; wave's WHOLE edge set sorted slice-major
// (slice = col>>13 -> XCD L2 phase lock). Single-batch phase-separated body:
// [8 scalar epk loads; 8 gathers; convert; pin] then [wave-uniform run
// accumulate; plain LDS float2 RMW flush]. NOTE (r11 lesson): deeper ILP
// (2-deep asm pipeline) BREAKS the emergent inter-wave slice-phase lock
// (FETCH 240->290MB, dur +23%) — latency exposure IS the sync mechanism.
// NO LDS atomics (gfx950 LDS fp atomics ~190cy/instr, r2/r6).
// Padded per wave to %16; epk = Tbyteoff | dloc (3 bits).
static constexpr int NPW = 8;                          // nodes per wave
static constexpr int NW2 = N / NPW;                    // 12500 (exact)
static constexpr int AGG2_BLOCKS = NW2 / 4;            // 3125 (exact)
static constexpr int NSLICE = ((N - 1) >> 13) + 1;     // 13
static constexpr int NBKT = NSLICE * NPW;              // 104 buckets/wave
static constexpr int BNRED_PER = (AGG2_BLOCKS + 63) / 64; // 49

// ---------------- workspace layout ----------------
static constexpr size_t OFF_TOT_D = 0;              // NBUCK int
static constexpr size_t OFF_TOT_S = 3328;           // NBUCK int
static constexpr size_t OFF_DBASE = 6656;           // NBUCK+1 int
static constexpr size_t OFF_SBASE = 9984;           // NBUCK+1 int
static constexpr size_t OFF_CVEC  = 15360;          // 128 f32
static constexpr size_t OFF_WT    = 16384;          // 128*128 bf16
static constexpr size_t OFF_PBASE = 49152;          // NBUCK+1 int (padded bucket bases)
static constexpr size_t OFF_PTOT  = 53248;          // NBUCK int (padded bucket totals)
static constexpr size_t OFF_BNP2  = 82944;          // 64*256 f32 (ends 148480)
static constexpr size_t OFF_EB    = 149504;         // (16*NBUCK+1) int per-wave padded bases
static constexpr size_t OFF_NORM_S= 2245632;        // N f32
static constexpr size_t OFF_NORM_D= 2645632;        // N f32
static constexpr size_t OFF_RP    = 3045632;        // N+1 int
static constexpr size_t OFF_CNT_D = 3445760;        // NBLK*NBUCK int; reused as bnp
static constexpr size_t OFF_BNP   = OFF_CNT_D;      // AGG2_BLOCKS*256 f32 = 3.2MB
static constexpr size_t OFF_CNT_S = 4246528;        // NBLK*NBUCK int
static constexpr size_t OFF_OFFD  = 5047296;        // NBLK*NBUCK int
static constexpr size_t OFF_OFFS  = 5848064;        // NBLK*NBUCK int
static constexpr size_t OFF_COL   = 6648832;        // E int (6648832..19448832)
static constexpr size_t OFF_EPK   = 19448832;       // padded edge stream; cap
                                                    // 4*(E+15*NW2)=13.55MB < 15.6MB region
static constexpr size_t OFF_SRCB  = 19448832;       // E uchar (dead after build; epk reuses)
static constexpr size_t OFF_PAIRS = 22648832;       // E uint (dead after build; epk spills in)
static constexpr size_t OFF_H     = 35448832;       // N*128 bf16
static constexpr size_t OFF_T     = 61048832;       // N*128 bf16
static constexpr unsigned T_OFFU  = 61048832u;
// Dummy rows: P_DUMMY in the col region (dead after k_eprep); its 64f image
// (P_DUMMY>>1)+C64 in the dead gap [35048832,35448832). Low 8 bits of P_DUMMY = 0
// (dloc 0 -> adds +0.0f to node n0: harmless). Zeroed by layer-1 k_wprep block 0.
static constexpr unsigned P_DUMMY  = 9437184u;      // 256B zero row (ws-relative)
static constexpr unsigned C64      = 30524416u;     // OFF_T/2 : agg64 rebase
static constexpr size_t OFF_DUM128 = 9437184;       // == P_DUMMY
static constexpr size_t OFF_DUM64  = 35243008;      // == (P_DUMMY>>1)+C64

using short8  = __attribute__((ext_vector_type(8))) short;
using float4v = __attribute__((ext_vector_type(4))) float;

__device__ inline float bflo(unsigned v) { return __uint_as_float(v << 16); }
__device__ inline float bfhi(unsigned v) { return __uint_as_float(v & 0xffff0000u); }
__device__ inline unsigned short bfbits(float x) {
    __hip_bfloat16 h = __float2bfloat16(x);
    return *reinterpret_cast<unsigned short*>(&h);
}

// ---- pass 1: per-block privatized bucket histograms (LDS atomics only) ----
__global__ __launch_bounds__(256) void k_count(const int* __restrict__ src,
                                               const int* __restrict__ dst,
                                               int* __restrict__ cnt_s,
                                               int* __restrict__ cnt_d) {
    __shared__ int hs[NBUCK], hd[NBUCK];
    int tid = threadIdx.x, blk = blockIdx.x;
    for (int b = tid; b < NBUCK; b += 256) { hs[b] = 0; hd[b] = 0; }
    __syncthreads();
    int e0 = blk * CHUNK, e1 = min(E, e0 + CHUNK);
    for (int e = e0 + tid; e < e1; e += 256) {
        atomicAdd(&hs[src[e] >> 7], 1);
        atomicAdd(&hd[dst[e] >> 7], 1);
    }
    __syncthreads();
    for (int b = tid; b < NBUCK; b += 256) {
        cnt_s[blk * NBUCK + b] = hs[b];
        cnt_d[blk * NBUCK + b] = hd[b];
    }
}

// ---- pass 2a: per-bucket scan over the 256 counting blocks ----
__global__ __launch_bounds__(256) void k_scanA2(const int* __restrict__ cnt_d,
                                                const int* __restrict__ cnt_s,
                                                int* __restrict__ offd,
                                                int* __restrict__ offs,
                                                int* __restrict__ tot_d,
                                                int* __restrict__ tot_s) {
    __shared__ int sd[256];
    int which = (blockIdx.x >= NBUCK) ? 1 : 0;
    int b = blockIdx.x - which * NBUCK;
    const int* cnt = which ? cnt_s : cnt_d;
    int* off = which ? offs : offd;
    int* tot = which ? tot_s : tot_d;
    int tid = threadIdx.x;
    int v = cnt[tid * NBUCK + b];
    sd[tid] = v;
    __syncthreads();
    for (int o = 1; o < 256; o <<= 1) {
        int t = (tid >= o) ? sd[tid - o] : 0;
        __syncthreads();
        sd[tid] += t;
        __syncthreads();
    }
    off[tid * NBUCK + b] = sd[tid] - v;
    if (tid == 255) tot[b] = sd[255];
}

// ---- pass 2b: scan bucket totals -> bases ----
__global__ __launch_bounds__(1024) void k_scanB(const int* __restrict__ tot_d,
                                                const int* __restrict__ tot_s,
                                                int* __restrict__ dbase,
                                                int* __restrict__ sbase) {
    __shared__ int sd[1024], ss[1024];
    int tid = threadIdx.x;
    int vd = (tid < NBUCK) ? tot_d[tid] : 0;
    int vs = (tid < NBUCK) ? tot_s[tid] : 0;
    sd[tid] = vd; ss[tid] = vs;
    __syncthreads();
    for (int o = 1; o < 1024; o <<= 1) {
        int td = (tid >= o) ? sd[tid - o] : 0;
        int ts = (tid >= o) ? ss[tid - o] : 0;
        __syncthreads();
        sd[tid] += td; ss[tid] += ts;
        __syncthreads();
    }
    if (tid < NBUCK) { dbase[tid] = sd[tid] - vd; sbase[tid] = ss[tid] - vs; }
    if (tid == 0) { dbase[NBUCK] = E; sbase[NBUCK] = E; }
}

// ---- pass 3: deterministic-offset scatter ----
__global__ __launch_bounds__(256) void k_scatter(const int* __restrict__ src,
                                                 const int* __restrict__ dst,
                                                 const int* __restrict__ dbase,
                                                 const int* __restrict__ sbase,
                                                 const int* __restrict__ offd,
                                                 const int* __restrict__ offs,
                                                 unsigned* __restrict__ pairs,
                                                 unsigned char* __restrict__ srcb) {
    __shared__ int cd[NBUCK], cs[NBUCK];
    int tid = threadIdx.x, blk = blockIdx.x;
    for (int b = tid; b < NBUCK; b += 256) {
        cd[b] = dbase[b] + offd[blk * NBUCK + b];
        cs[b] = sbase[b] + offs[blk * NBUCK + b];
    }
    __syncthreads();
    int e0 = blk * CHUNK, e1 = min(E, e0 + CHUNK);
    for (int e = e0 + tid; e < e1; e += 256) {
        int s = src[e], d = dst[e];
        int pd = atomicAdd(&cd[d >> 7], 1);
        pairs[pd] = (unsigned)s | ((unsigned)(d & 127) << 20);
        int ps = atomicAdd(&cs[s >> 7], 1);
        srcb[ps] = (unsigned char)(s & 127);
    }
}

// ---- pass 4: per-bucket degrees/norms/rp/col + per-wave padded bases ----
__global__ __launch_bounds__(256) void k_build(const unsigned* __restrict__ pairs,
                                               const unsigned char* __restrict__ srcb,
                                               const int* __restrict__ dbase,
                                               const int* __restrict__ sbase,
                                               int* __restrict__ rp,
                                               float* __restrict__ norm_d,
                                               float* __restrict__ norm_s,
                                               int* __restrict__ col,
                                               int* __restrict__ eb,
                                               int* __restrict__ ptot) {
    __shared__ int cnt[128], scn[128], lcur[128];
    __shared__ int wpe[16], wps[16];
    int b = blockIdx.x, tid = threadIdx.x, node0 = b << 7;
    int nmax = min(128, N - node0);
    if (tid < 128) cnt[tid] = 0;
    __syncthreads();
    int sb = sbase[b], se = sbase[b + 1];
    for (int e = sb + tid; e < se; e += 256) atomicAdd(&cnt[srcb[e]], 1);
    __syncthreads();
    if (tid < nmax) norm_s[node0 + tid] = rsqrtf(fmaxf((float)cnt[tid], 1.0f));
    __syncthreads();
    if (tid < 128) cnt[tid] = 0;
    __syncthreads();
    int beg = dbase[b], end = dbase[b + 1];
    for (int e = beg + tid; e < end; e += 256) atomicAdd(&cnt[pairs[e] >> 20], 1);
    __syncthreads();
    if (tid < 128) scn[tid] = cnt[tid];
    if (tid < 16) {   // per-wave (8-node chunk) padded totals (%16 for 2-deep pipeline)
        int s = 0;
#pragma unroll
        for (int i = 0; i < 8; ++i) s += cnt[tid * 8 + i];
        wpe[tid] = (s + 15) & ~15;
    }
    __syncthreads();
    for (int o = 1; o < 128; o <<= 1) {
        int t = (tid < 128 && tid >= o) ? scn[tid - o] : 0;
        __syncthreads();
        if (tid < 128) scn[tid] += t;
        __syncthreads();
    }
    if (tid == 0) {
        int run = 0;
#pragma unroll
        for (int k = 0; k < 16; ++k) { int c = wpe[k]; wps[k] = run; run += c; }
        ptot[b] = run;
    }
    __syncthreads();
    if (tid < 16) eb[b * 16 + tid] = wps[tid];      // local padded excl (finalized in eprep)
    if (tid < nmax) {
        int excl = beg + scn[tid] - cnt[tid];
        rp[node0 + tid] = excl;
        lcur[tid] = excl;
        norm_d[node0 + tid] = rsqrtf(fmaxf((float)cnt[tid], 1.0f));
    }
    if (b == 0 && tid == 0) rp[N] = E;
    __syncthreads();
    for (int e = beg + tid; e < end; e += 256) {
        unsigned p = pairs[e];
        int pos = atomicAdd(&lcur[p >> 20], 1);
        col[pos] = (int)(p & 0xFFFFFu);
    }
}

// ---- scan padded bucket totals -> pbase; finalize eb[NW2] ----
__global__ __launch_bounds__(1024) void k_scanP(const int* __restrict__ ptot,
                                                int* __restrict__ pbase,
                                                int* __restrict__ eb) {
    __shared__ int sd[1024];
    int tid = threadIdx.x;
    int v = (tid < NBUCK) ? ptot[tid] : 0;
    sd[tid] = v;
    __syncthreads();
    for (int o = 1; o < 1024; o <<= 1) {
        int t = (tid >= o) ? sd[tid - o] : 0;
        __syncthreads();
        sd[tid] += t;
        __syncthreads();
    }
    if (tid < NBUCK) pbase[tid] = sd[tid] - v;
    if (tid == 1023) { pbase[NBUCK] = sd[1023]; eb[NW2] = sd[1023]; }
}

// ---- edge prep: per-wave (slice,dloc)-sorted padded segment ----
// epk = T_OFF + col*256 + dloc ; wave-set slice-major order = L2 phase lock.
__global__ __launch_bounds__(256) void k_eprep(const int* __restrict__ col,
                                               const int* __restrict__ rp,
                                               const int* __restrict__ pbase,
                                               int* __restrict__ eb,
                                               unsigned* __restrict__ epk) {
    __shared__ int cnt[4][NBKT];
    int tid = threadIdx.x, wave = tid >> 6, lane = tid & 63;
    int w = blockIdx.x * 4 + wave;
    int n0 = w * NPW;
    for (int k = lane; k < NBKT; k += 64) cnt[wave][k] = 0;
    int rpl[NPW + 1];
#pragma unroll
    for (int j = 0; j <= NPW; ++j) rpl[j] = rp[n0 + j];
    // per-wave private LDS + in-order DS pipe -> no barriers needed
#pragma unroll
    for (int j = 0; j < NPW; ++j)
        for (int e = rpl[j] + lane; e < rpl[j + 1]; e += 64)
            atomicAdd(&cnt[wave][(((unsigned)col[e]) >> 13) * NPW + j], 1);
    if (lane == 0) {
        int base = pbase[n0 >> 7] + eb[w];
        eb[w] = base;                                  // finalize global padded base
        int run = base;
        for (int k = 0; k < NBKT; ++k) { int c = cnt[wave][k]; cnt[wave][k] = run; run += c; }
        int padend = base + ((rpl[NPW] - rpl[0] + 15) & ~15);
        for (int q = run; q < padend; ++q) epk[q] = P_DUMMY;
    }
#pragma unroll
    for (int j = 0; j < NPW; ++j)
        for (int e = rpl[j] + lane; e < rpl[j + 1]; e += 64) {
            unsigned c = (unsigned)col[e];
            int pos = atomicAdd(&cnt[wave][(c >> 13) * NPW + j], 1);
            epk[pos] = T_OFFU + (c << 8) + (unsigned)j;
        }
}

// ---- W prep (fused BN finalize); layer-1 instance also zeroes the dummy rows ----
template <bool AFFINE>
__global__ __launch_bounds__(64) void k_wprep(const float* __restrict__ W,
                                              const float* __restrict__ part2, // 64 x 256
                                              const float* __restrict__ gamma,
                                              const float* __restrict__ beta,
                                              int fout,
                                              unsigned short* __restrict__ Wt,
                                              float* __restrict__ cvec,
                                              unsigned* __restrict__ dz256,
                                              unsigned* __restrict__ dz64) {
    int n = blockIdx.x, k = threadIdx.x;
    if (!AFFINE && n == 0) {
        dz256[k] = 0u;                 // 64 uints = 256 B @ OFF_DUM128
        if (k < 32) dz64[k] = 0u;      // 32 uints = 128 B @ OFF_DUM64
    }
    float a0 = 1.f, c0 = 0.f, a1 = 1.f, c1 = 0.f;
    if (AFFINE) {
        int l0 = ((k & 1) ? 128 : 0) + (k >> 1);
        int m0 = ((k & 1) ? 192 : 64) + (k >> 1);
        int l1 = l0 + 32, m1 = m0 + 32;
        float s0 = 0.f, q0 = 0.f, s1 = 0.f, q1 = 0.f;
        for (int b = 0; b < 64; ++b) {
            const float* r = part2 + b * 256;
            s0 += r[l0]; q0 += r[m0];
            s1 += r[l1]; q1 += r[m1];
        }
        float mu0 = s0 * (1.0f / N), var0 = q0 * (1.0f / N) - mu0 * mu0;
        a0 = gamma[k] * rsqrtf(var0 + BN_EPS);
        c0 = beta[k] - mu0 * a0;
        float mu1 = s1 * (1.0f / N), var1 = q1 * (1.0f / N) - mu1 * mu1;
        a1 = gamma[k + 64] * rsqrtf(var1 + BN_EPS);
        c1 = beta[k + 64] - mu1 * a1;
    }
    float w0 = W[k * fout + n], w1 = W[(k + 64) * fout + n];
    Wt[n * 128 + k] = bfbits(a0 * w0);
    Wt[n * 128 + k + 64] = bfbits(a1 * w1);
    float cv = c0 * w0 + c1 * w1;
    for (int o = 32; o; o >>= 1) cv += __shfl_xor(cv, o);
    if (k == 0) cvec[n] = cv;
}

// ---- MFMA GEMM: T = ns .* (Xbf16 @ Wt^T + cvec) ----
template <typename TIn, int FOUT>
__global__ __launch_bounds__(256) void k_gemm(const TIn* __restrict__ in,
                                              const unsigned short* __restrict__ Wt,
                                              const float* __restrict__ cvec,
                                              const float* __restrict__ ns,
                                              unsigned short* __restrict__ out) {
    constexpr int PK = 72;
    __shared__ __align__(16) unsigned short Xs[128 * PK];
    __shared__ __align__(16) unsigned short Wsh[FOUT * PK];
    const int tid = threadIdx.x;
    const int r0 = blockIdx.x * 128;
    const int wave = tid >> 6, lane = tid & 63;
    const int l16 = lane & 15, quad = lane >> 4;
    constexpr int MT = (FOUT == 128) ? 4 : 2;
    constexpr int NT = 4;
    const int wm = (FOUT == 128) ? (wave >> 1) : wave;
    const int wn = (FOUT == 128) ? (wave & 1) : 0;
    const int mbase = wm * (MT * 16);
    const int nbase = wn * 64;

    float4v acc[MT][NT];
#pragma unroll
    for (int mt = 0; mt < MT; ++mt)
#pragma unroll
        for (int nt = 0; nt < NT; ++nt) acc[mt][nt] = (float4v){0.f, 0.f, 0.f, 0.f};

    for (int kb = 0; kb < 128; kb += 64) {
        __syncthreads();
        for (int i = tid; i < 128 * 8; i += 256) {
            int row = i >> 3, j = i & 7;
            int grow = r0 + row;
            if constexpr (sizeof(TIn) == 4) {
                short8 p = {0, 0, 0, 0, 0, 0, 0, 0};
                if (grow < N) {
                    const float* g = (const float*)in + (size_t)grow * 128 + kb + j * 8;
                    float4 f0 = *(const float4*)g;
                    float4 f1 = *(const float4*)(g + 4);
                    p[0] = (short)bfbits(f0.x); p[1] = (short)bfbits(f0.y);
                    p[2] = (short)bfbits(f0.z); p[3] = (short)bfbits(f0.w);
                    p[4] = (short)bfbits(f1.x); p[5] = (short)bfbits(f1.y);
                    p[6] = (short)bfbits(f1.z); p[7] = (short)bfbits(f1.w);
                }
                *(short8*)&Xs[row * PK + j * 8] = p;
            } else {
                uint4 v = make_uint4(0, 0, 0, 0);
                if (grow < N)
                    v = *(const uint4*)((const unsigned short*)in + (size_t)grow * 128 + kb + j * 8);
                *(uint4*)&Xs[row * PK + j * 8] = v;
            }
        }
        for (int i = tid; i < FOUT * 8; i += 256) {
            int n = i >> 3, j = i & 7;
            uint4 v = *(const uint4*)&Wt[n * 128 + kb + j * 8];
            *(uint4*)&Wsh[n * PK + j * 8] = v;
        }
        __syncthreads();
#pragma unroll
        for (int ks = 0; ks < 64; ks += 32) {
            short8 af[MT], bfr[NT];
#pragma unroll
            for (int mt = 0; mt < MT; ++mt)
                af[mt] = *(const short8*)&Xs[(mbase + mt * 16 + l16) * PK + ks + quad * 8];
#pragma unroll
            for (int nt = 0; nt < NT; ++nt)
                bfr[nt] = *(const short8*)&Wsh[(nbase + nt * 16 + l16) * PK + ks + quad * 8];
#pragma unroll
            for (int mt = 0; mt < MT; ++mt)
#pragma unroll
                for (int nt = 0; nt < NT; ++nt)
                    acc[mt][nt] = __builtin_amdgcn_mfma_f32_16x16x32_bf16(
                        af[mt], bfr[nt], acc[mt][nt], 0, 0, 0);
        }
    }
    float cv[NT];
#pragma unroll
    for (int nt = 0; nt < NT; ++nt) cv[nt] = cvec[nbase + nt * 16 + l16];
#pragma unroll
    for (int mt = 0; mt < MT; ++mt) {
#pragma unroll
        for (int r = 0; r < 4; ++r) {
            int row = r0 + mbase + mt * 16 + quad * 4 + r;
            if (row < N) {
                float s = ns[row];
#pragma unroll
                for (int nt = 0; nt < NT; ++nt)
                    out[(size_t)row * FOUT + nbase + nt * 16 + l16] =
                        bfbits((acc[mt][nt][r] + cv[nt]) * s);
            }
        }
    }
}

// ------- aggregation (128 feats): slice-major wave set; 2-deep pipelined batches -------
__global__ __launch_bounds__(256, 8) void k_agg128s(const char* wsb,
                                                    const int* __restrict__ eb,
                                                    const unsigned* __restrict__ epk,
                                                    const float* __restrict__ norm_d,
                                                    const float* __restrict__ bias,
                                                    unsigned* Hu,          // N x 64 uints
                                                    float* __restrict__ part) {
    // acc[wave][dloc]: float2 per lane (feats 2l, 2l+1)
    __shared__ float acc[4][NPW][128];                // 16 KB; red overlays later
    const int tid = threadIdx.x, wave = tid >> 6, lane = tid & 63;
    const int w = blockIdx.x * 4 + wave;
    const int n0 = w * NPW;
    float2* a2 = reinterpret_cast<float2*>(&acc[wave][0][0]) + lane; // a2[dloc*64]
#pragma unroll
    for (int j = 0; j < NPW; ++j) a2[j * 64] = make_float2(0.f, 0.f);
    const unsigned lane4 = (unsigned)(lane << 2);
    int e = __builtin_amdgcn_readfirstlane(eb[w]);
    const int e1 = __builtin_amdgcn_readfirstlane(eb[w + 1]);
    int cur = 0;
    float a0 = 0.f, a1 = 0.f;
    if (e < e1) {
        unsigned pa[8], pb[8];
        int da[8], db[8];
        float fa0[8], fa1[8], fb0[8], fb1[8];
        // prologue: issue batch A
#pragma unroll
        for (int i = 0; i < 8; ++i) pa[i] = epk[e + i];
#pragma unroll
        for (int i = 0; i < 8; ++i) da[i] = __builtin_amdgcn_readfirstlane((int)(pa[i] & 7u));
#pragma unroll
        for (int i = 0; i < 8; ++i) {
            unsigned v = *(const unsigned*)(wsb + (pa[i] & 0xFFFFFF00u) + lane4);
            fa0[i] = bflo(v); fa1[i] = bfhi(v);
        }
        for (; e + 16 <= e1; e += 16) {
            // issue batch B (e+8)
#pragma unroll
            for (int i = 0; i < 8; ++i) pb[i] = epk[e + 8 + i];
#pragma unroll
            for (int i = 0; i < 8; ++i) db[i] = __builtin_amdgcn_readfirstlane((int)(pb[i] & 7u));
#pragma unroll
            for (int i = 0; i < 8; ++i) {
                unsigned v = *(const unsigned*)(wsb + (pb[i] & 0xFFFFFF00u) + lane4);
                fb0[i] = bflo(v); fb1[i] = bfhi(v);
            }
            // pin A, process A
#pragma unroll
            for (int i = 0; i < 8; ++i) asm volatile("" :: "v"(fa0[i]), "v"(fa1[i]));
            __builtin_amdgcn_sched_barrier(0);
#pragma unroll
            for (int i = 0; i < 8; ++i) {
                if (da[i] != cur) {                   // wave-uniform scalar branch
                    float2 t = a2[cur * 64]; t.x += a0; t.y += a1; a2[cur * 64] = t;
                    cur = da[i]; a0 = 0.f; a1 = 0.f;
                }
                a0 += fa0[i]; a1 += fa1[i];
            }
            __builtin_amdgcn_sched_barrier(0);
            // issue next batch A (clamped on final iteration; never processed then)
            {
                int en = (e + 16 < e1) ? (e + 16) : (e1 - 8);
#pragma unroll
                for (int i = 0; i < 8; ++i) pa[i] = epk[en + i];
#pragma unroll
                for (int i = 0; i < 8; ++i) da[i] = __builtin_amdgcn_readfirstlane((int)(pa[i] & 7u));
#pragma unroll
                for (int i = 0; i < 8; ++i) {
                    unsigned v = *(const unsigned*)(wsb + (pa[i] & 0xFFFFFF00u) + lane4);
                    fa0[i] = bflo(v); fa1[i] = bfhi(v);
                }
            }
            // pin B, process B
#pragma unroll
            for (int i = 0; i < 8; ++i) asm volatile("" :: "v"(fb0[i]), "v"(fb1[i]));
            __builtin_amdgcn_sched_barrier(0);
#pragma unroll
            for (int i = 0; i < 8; ++i) {
                if (db[i] != cur) {
                    float2 t = a2[cur * 64]; t.x += a0; t.y += a1; a2[cur * 64] = t;
                    cur = db[i]; a0 = 0.f; a1 = 0.f;
                }
                a0 += fb0[i]; a1 += fb1[i];
            }
            __builtin_amdgcn_sched_barrier(0);
        }
        // final run flush
        float2 t = a2[cur * 64]; t.x += a0; t.y += a1; a2[cur * 64] = t;
    }
    // epilogue: per-node outputs + BN partials (own wave's acc only)
    float s0 = 0.f, q0 = 0.f, s1 = 0.f, q1 = 0.f;
    const float bb0 = bias[2 * lane], bb1 = bias[2 * lane + 1];
#pragma unroll
    for (int j = 0; j < NPW; ++j) {
        int n = n0 + j;
        float2 a = a2[j * 64];
        float nd = norm_d[n];
        float r0 = fmaxf(a.x * nd + bb0, 0.0f);
        float r1 = fmaxf(a.y * nd + bb1, 0.0f);
        Hu[(size_t)n * 64 + lane] = ((unsigned)bfbits(r1) << 16) | bfbits(r0);
        s0 += r0; q0 += r0 * r0; s1 += r1; q1 += r1 * r1;
    }
    __syncthreads();                     // everyone done reading their acc
    float* red = &acc[0][0][0];          // reuse first 1024 floats as reduce stage
    red[wave * 256 + lane] = s0;
    red[wave * 256 + 64 + lane] = q0;
    red[wave * 256 + 128 + lane] = s1;
    red[wave * 256 + 192 + lane] = q1;
    __syncthreads();
    float t = red[tid] + red[256 + tid] + red[512 + tid] + red[768 + tid];
    part[blockIdx.x * 256 + tid] = t;
}

// hierarchical BN partial reduce: AGG2_BLOCKS rows -> 64 rows
__global__ __launch_bounds__(256) void k_bnred(const float* __restrict__ part,
                                               float* __restrict__ part2) {
    int b = blockIdx.x, tid = threadIdx.x;
    float s = 0.f;
    for (int i = 0; i < BNRED_PER; ++i) {
        int r = b * BNRED_PER + i;
        if (r < AGG2_BLOCKS) s += part[r * 256 + tid];
    }
    part2[b * 256 + tid] = s;
}

// ------- aggregation (64 feats) + log_softmax: same 2-deep pipelined structure -------
__global__ __launch_bounds__(256, 8) void k_agg64s(const char* wsb,
                                                   const int* __restrict__ eb,
                                                   const unsigned* __restrict__ epk,
                                                   const float* __restrict__ norm_d,
                                                   const float* __restrict__ b3,
                                                   float* __restrict__ out) {
    __shared__ float acc[4][NPW][64];                 // 8 KB
    const int tid = threadIdx.x, wave = tid >> 6, lane = tid & 63;
    const int w = blockIdx.x * 4 + wave;
    const int n0 = w * NPW;
    float* a1p = &acc[wave][0][0] + lane;             // a1p[dloc*64]
#pragma unroll
    for (int j = 0; j < NPW; ++j) a1p[j * 64] = 0.f;
    const unsigned lane2 = (unsigned)(lane << 1);
    int e = __builtin_amdgcn_readfirstlane(eb[w]);
    const int e1 = __builtin_amdgcn_readfirstlane(eb[w + 1]);
    int cur = 0;
    float a0 = 0.f;
    if (e < e1) {
        unsigned pa[8], pb[8];
        int da[8], db[8];
        float fa[8], fb[8];
#pragma unroll
        for (int i = 0; i < 8; ++i) pa[i] = epk[e + i];
#pragma unroll
        for (int i = 0; i < 8; ++i) da[i] = __builtin_amdgcn_readfirstlane((int)(pa[i] & 7u));
#pragma unroll
        for (int i = 0; i < 8; ++i) {
            unsigned u = *(const unsigned short*)(wsb + (((pa[i] >> 1) & 0xFFFFFF80u) + C64) + lane2);
            fa[i] = __uint_as_float(u << 16);
        }
        for (; e + 16 <= e1; e += 16) {
#pragma unroll
            for (int i = 0; i < 8; ++i) pb[i] = epk[e + 8 + i];
#pragma unroll
            for (int i = 0; i < 8; ++i) db[i] = __builtin_amdgcn_readfirstlane((int)(pb[i] & 7u));
#pragma unroll
            for (int i = 0; i < 8; ++i) {
                unsigned u = *(const unsigned short*)(wsb + (((pb[i] >> 1) & 0xFFFFFF80u) + C64) + lane2);
                fb[i] = __uint_as_float(u << 16);
            }
#pragma unroll
            for (int i = 0; i < 8; ++i) asm volatile("" :: "v"(fa[i]));
            __builtin_amdgcn_sched_barrier(0);
#pragma unroll
            for (int i = 0; i < 8; ++i) {
                if (da[i] != cur) { a1p[cur * 64] += a0; cur = da[i]; a0 = 0.f; }
                a0 += fa[i];
            }
            __builtin_amdgcn_sched_barrier(0);
            {
                int en = (e + 16 < e1) ? (e + 16) : (e1 - 8);
#pragma unroll
                for (int i = 0; i < 8; ++i) pa[i] = epk[en + i];
#pragma unroll
                for (int i = 0; i < 8; ++i) da[i] = __builtin_amdgcn_readfirstlane((int)(pa[i] & 7u));
#pragma unroll
                for (int i = 0; i < 8; ++i) {
                    unsigned u = *(const unsigned short*)(wsb + (((pa[i] >> 1) & 0xFFFFFF80u) + C64) + lane2);
                    fa[i] = __uint_as_float(u << 16);
                }
            }
#pragma unroll
            for (int i = 0; i < 8; ++i) asm volatile("" :: "v"(fb[i]));
            __builtin_amdgcn_sched_barrier(0);
#pragma unroll
            for (int i = 0; i < 8; ++i) {
                if (db[i] != cur) { a1p[cur * 64] += a0; cur = db[i]; a0 = 0.f; }
                a0 += fb[i];
            }
            __builtin_amdgcn_sched_barrier(0);
        }
        a1p[cur * 64] += a0;
    }
    const float bb = b3[lane];
#pragma unroll
    for (int j = 0; j < NPW; ++j) {
        int n = n0 + j;
        float z = a1p[j * 64] * norm_d[n] + bb;
        float m = z;
        for (int o = 32; o; o >>= 1) m = fmaxf(m, __shfl_xor(m, o));
        float ex = __expf(z - m);
        float ssum = ex;
        for (int o = 32; o; o >>= 1) ssum += __shfl_xor(ssum, o);
        out[(size_t)n * 64 + lane] = z - m - __logf(ssum);
    }
}

extern "C" void kernel_launch(void* const* d_in, const int* in_sizes, int n_in,
                              void* d_out, int out_size, void* d_ws, size_t ws_size,
                              hipStream_t stream) {
    const float* x  = (const float*)d_in[0];
    const int* src  = (const int*)d_in[1];
    const int* dst  = (const int*)d_in[2];
    const float* W1 = (const float*)d_in[3];
    const float* b1 = (const float*)d_in[4];
    const float* W2 = (const float*)d_in[5];
    const float* b2 = (const float*)d_in[6];
    const float* W3 = (const float*)d_in[7];
    const float* b3 = (const float*)d_in[8];
    const float* g1 = (const float*)d_in[9];
    const float* be1= (const float*)d_in[10];
    const float* g2 = (const float*)d_in[11];
    const float* be2= (const float*)d_in[12];
    float* out = (float*)d_out;

    char* ws = (char*)d_ws;
    int* tot_d = (int*)(ws + OFF_TOT_D);
    int* tot_s = (int*)(ws + OFF_TOT_S);
    int* dbase = (int*)(ws + OFF_DBASE);
    int* sbase = (int*)(ws + OFF_SBASE);
    float* cvec = (float*)(ws + OFF_CVEC);
    unsigned short* Wt = (unsigned short*)(ws + OFF_WT);
    int* pbase = (int*)(ws + OFF_PBASE);
    int* ptot  = (int*)(ws + OFF_PTOT);
    float* bnp2 = (float*)(ws + OFF_BNP2);
    int* eb = (int*)(ws + OFF_EB);
    float* bnp = (float*)(ws + OFF_BNP);
    float* norm_s = (float*)(ws + OFF_NORM_S);
    float* norm_d = (float*)(ws + OFF_NORM_D);
    int* rp = (int*)(ws + OFF_RP);
    int* cnt_d = (int*)(ws + OFF_CNT_D);
    int* cnt_s = (int*)(ws + OFF_CNT_S);
    int* offd = (int*)(ws + OFF_OFFD);
    int* offs = (int*)(ws + OFF_OFFS);
    int* col = (int*)(ws + OFF_COL);
    unsigned char* srcb = (unsigned char*)(ws + OFF_SRCB);
    unsigned* pairs = (unsigned*)(ws + OFF_PAIRS);
    unsigned* epk = (unsigned*)(ws + OFF_EPK);   // overlays srcb+pairs (dead post-build)
    unsigned* dz256 = (unsigned*)(ws + OFF_DUM128);
    unsigned* dz64  = (unsigned*)(ws + OFF_DUM64);
    unsigned short* H = (unsigned short*)(ws + OFF_H);
    unsigned short* T = (unsigned short*)(ws + OFF_T);

    // CSR build — zero global atomics
    k_count<<<NBLK, 256, 0, stream>>>(src, dst, cnt_s, cnt_d);
    k_scanA2<<<2 * NBUCK, 256, 0, stream>>>(cnt_d, cnt_s, offd, offs, tot_d, tot_s);
    k_scanB<<<1, 1024, 0, stream>>>(tot_d, tot_s, dbase, sbase);
    k_scatter<<<NBLK, 256, 0, stream>>>(src, dst, dbase, sbase, offd, offs, pairs, srcb);
    k_build<<<NBUCK, 256, 0, stream>>>(pairs, srcb, dbase, sbase, rp, norm_d, norm_s, col, eb, ptot);
    k_scanP<<<1, 1024, 0, stream>>>(ptot, pbase, eb);
    k_eprep<<<AGG2_BLOCKS, 256, 0, stream>>>(col, rp, pbase, eb, epk);

    const int gemm_grid = (N + 127) / 128;

    // Layer 1 (wprep block 0 zeroes the dummy rows; runs after eprep, before agg)
    k_wprep<false><<<128, 64, 0, stream>>>(W1, nullptr, nullptr, nullptr, 128, Wt, cvec, dz256, dz64);
    k_gemm<float, 128><<<gemm_grid, 256, 0, stream>>>(x, Wt, cvec, norm_s, T);
    k_agg128s<<<AGG2_BLOCKS, 256, 0, stream>>>(ws, eb, epk, norm_d, b1, (unsigned*)H, bnp);
    k_bnred<<<64, 256, 0, stream>>>(bnp, bnp2);

    // Layer 2 (wprep fuses BN finalize from bnp2)
    k_wprep<true><<<128, 64, 0, stream>>>(W2, bnp2, g1, be1, 128, Wt, cvec, nullptr, nullptr);
    k_gemm<__hip_bfloat16, 128><<<gemm_grid, 256, 0, stream>>>((const __hip_bfloat16*)H, Wt, cvec, norm_s, T);
    k_agg128s<<<AGG2_BLOCKS, 256, 0, stream>>>(ws, eb, epk, norm_d, b2, (unsigned*)H, bnp);
    k_bnred<<<64, 256, 0, stream>>>(bnp, bnp2);

    // Layer 3 (64 outputs) + log_softmax
    k_wprep<true><<<64, 64, 0, stream>>>(W3, bnp2, g2, be2, 64, Wt, cvec, nullptr, nullptr);
    k_gemm<__hip_bfloat16, 64><<<gemm_grid, 256, 0, stream>>>((const __hip_bfloat16*)H, Wt, cvec, norm_s, T);
    k_agg64s<<<AGG2_BLOCKS, 256, 0, stream>>>(ws, eb, epk, norm_d, b3, out);
}